// Round 15
// baseline (4471.723 us; speedup 1.0000x reference)
//
#include <hip/hip_runtime.h>

// ---------------- problem constants ----------------
#define BB_ 32
#define SS_ 256
#define TD_ 63
#define EE_ 128
#define VV_ 32000

typedef unsigned short u16;
typedef unsigned int u32;
typedef unsigned long long u64;
typedef __attribute__((ext_vector_type(8))) short short8v;
typedef __attribute__((ext_vector_type(4))) float f32x4;

__device__ __forceinline__ float sigf(float x){ return 1.0f/(1.0f+__expf(-x)); }
__device__ __forceinline__ float tanhf_fast(float x){ return 1.0f - 2.0f/(__expf(2.0f*x)+1.0f); }
__device__ __forceinline__ u16 f2bf(float f){
  unsigned u = __float_as_uint(f);
  u += 0x7fff + ((u >> 16) & 1);
  return (u16)(u >> 16);
}
__device__ __forceinline__ u32 packbf(float a, float b){
  return (u32)f2bf(a) | ((u32)f2bf(b) << 16);
}
__device__ __forceinline__ float bflo(u32 v){ return __uint_as_float(v << 16); }
__device__ __forceinline__ float bfhi(u32 v){ return __uint_as_float(v & 0xffff0000u); }

// ---- coherent (agent-scope) payload accessors ----
__device__ __forceinline__ u32 aldu(const u32* p){
  return __hip_atomic_load(p, __ATOMIC_RELAXED, __HIP_MEMORY_SCOPE_AGENT);
}
__device__ __forceinline__ u64 ald64u(const u32* p){
  return __hip_atomic_load((const u64*)p, __ATOMIC_RELAXED, __HIP_MEMORY_SCOPE_AGENT);
}
__device__ __forceinline__ void astu(u32* p, u32 v){
  __hip_atomic_store(p, v, __ATOMIC_RELAXED, __HIP_MEMORY_SCOPE_AGENT);
}
__device__ __forceinline__ float aldf(const float* p){
  return __hip_atomic_load(p, __ATOMIC_RELAXED, __HIP_MEMORY_SCOPE_AGENT);
}
__device__ __forceinline__ void astf(float* p, float v){
  __hip_atomic_store(p, v, __ATOMIC_RELAXED, __HIP_MEMORY_SCOPE_AGENT);
}
__device__ __forceinline__ void vdrain(){ asm volatile("s_waitcnt vmcnt(0)" ::: "memory"); }

__device__ __forceinline__ short8v mkfrag(u64 a, u64 b){
  union { u32 u[4]; short8v v; } c;
  c.u[0] = (u32)a; c.u[1] = (u32)(a >> 32);
  c.u[2] = (u32)b; c.u[3] = (u32)(b >> 32);
  return c.v;
}

// 8-kk MFMA batch: A frags from LDS starting at kk=akk0; B direct from packed global
__device__ __forceinline__ f32x4 mma8(const char* ldsA, int akk0, const u32* brow,
                                      int boff, int lk, int l, f32x4 acc){
  u64 bq[16];
  #pragma unroll
  for (int k2 = 0; k2 < 8; k2++){
    int a = boff + k2*16 + lk*4;
    bq[2*k2]   = ald64u(brow + a);
    bq[2*k2+1] = ald64u(brow + a + 2);
  }
  #pragma unroll
  for (int k2 = 0; k2 < 8; k2++){
    short8v aF = *(const short8v*)(ldsA + (((akk0 + k2)*64) + l)*16);
    acc = __builtin_amdgcn_mfma_f32_16x16x32_bf16(aF, mkfrag(bq[2*k2], bq[2*k2+1]), acc, 0, 0, 0);
  }
  return acc;
}

// ---------------- d_out scratch layout (float offsets) ----------------
#define OFF_Z        0u
#define OFF_Y0       16777216u
#define OFF_Y1       20971520u
#define OFF_ZPRE     25165824u
#define OFF_H1ALL    29294592u
#define OFF_SRCE     30326784u
#define OFF_TGTE     31375360u
#define OFF_EPROJ    31633408u
#define OFF_ENCA0    33730560u
#define OFF_ENCA1    33992704u
#define OFF_DECA     34254848u
#define OFF_ATP      36352000u
#define OFF_E0H      36417536u
#define OFF_E0C      36433920u
#define OFF_E1H      36450304u
#define OFF_E1C      36466688u
#define OFF_H0P      36483072u
#define OFF_H1P      36499456u
#define OFF_CTXP     36515840u   // 4 partials x 8192 u32 (32768 fl)
#define OFF_CTXS     36548608u   // 128 f32
#define OFF_Y1P      36548736u   // 2097152 fl
#define OFF_HEXA     38645888u
#define OFF_HEXB     38662272u
#define OFF_BARS     38678656u

// ---------------- ws scratch layout (float offsets, fused path) ----------------
#define W_EPROJ   0u
#define W_ZPRE    2097152u
#define W_Y1P     6225920u
#define W_DECA    8323072u
#define W_ATP     10420224u
#define W_H0P     10485760u
#define W_H1P     10502144u
#define W_CTXP    10518528u      // 32768 fl
#define W_CTXS    10551296u      // 128 fl
#define W_H1ALL   10551424u
#define W_HIDP    11583616u
#define W_DBAR    11845760u
#define W_TOTAL   11847808u      // ~47.4 MB

// ---------------- fence-free barriers ----------------
__device__ __forceinline__ void icbar(unsigned* ctr, unsigned target){
  vdrain();
  __syncthreads();
  if (threadIdx.x == 0){
    __hip_atomic_fetch_add(ctr, 1u, __ATOMIC_RELAXED, __HIP_MEMORY_SCOPE_AGENT);
    while (__hip_atomic_load(ctr, __ATOMIC_RELAXED, __HIP_MEMORY_SCOPE_AGENT) < target)
      __builtin_amdgcn_s_sleep(1);
  }
  __syncthreads();
  asm volatile("" ::: "memory");
}

// decoder barrier v2: DISTRIBUTED detect — every block's wave0 polls the 16
// group-arrival counters directly (16 lanes, one load instr, __all). No root
// round-trip, no release stores. Root (Bid 127) additionally publishes the
// head-progress word after its own detect. Monotone counters => race-free.
__device__ __forceinline__ void icbar3(unsigned* db, unsigned gen, bool isRoot){
  vdrain();
  __syncthreads();
  int tid = threadIdx.x;
  unsigned g = (unsigned)blockIdx.x & 15u;
  if (tid == 0)
    __hip_atomic_fetch_add(&db[g*32], 1u, __ATOMIC_RELAXED, __HIP_MEMORY_SCOPE_AGENT);
  if (tid < 64){
    unsigned tgt = gen * 8u;
    for (;;){
      unsigned a = (tid < 16)
        ? __hip_atomic_load(&db[(unsigned)tid*32], __ATOMIC_RELAXED, __HIP_MEMORY_SCOPE_AGENT)
        : tgt;
      if (__all(a >= tgt)) break;
      __builtin_amdgcn_s_sleep(1);
    }
    if (isRoot && tid == 16)
      __hip_atomic_store(&db[1024], gen, __ATOMIC_RELAXED, __HIP_MEMORY_SCOPE_AGENT);
  }
  __syncthreads();
  asm volatile("" ::: "memory");
}

// ---------------- utility kernels ----------------
__global__ void k_zero(float* __restrict__ p, int n){
  int i = blockIdx.x*256 + threadIdx.x;
  if (i < n) p[i] = 0.f;
}

__global__ void k_gather(const int* __restrict__ src, const int* __restrict__ tgt,
                         const float* __restrict__ emb,
                         float* __restrict__ src_e, float* __restrict__ tgt_e){
  int idx = blockIdx.x*256 + threadIdx.x;
  const int total = (8192 + 2016) * 32;
  if (idx >= total) return;
  int row = idx >> 5, j = idx & 31;
  int tok; float* dst;
  if (row < 8192){
    int s = row >> 5, b = row & 31;
    tok = src[b*SS_ + s];
    dst = src_e + (size_t)row*EE_;
  } else {
    int r2 = row - 8192;
    int t = r2 >> 5, b = r2 & 31;
    tok = tgt[b*64 + t];
    dst = tgt_e + (size_t)r2*EE_;
  }
  float4 v = *(const float4*)(emb + (size_t)tok*EE_ + j*4);
  *(float4*)(dst + j*4) = v;
}

// encoder v2 A-fragment prep (proven)
__global__ void k_prep_encA(const float* __restrict__ W, u16* __restrict__ out){
  int idx = blockIdx.x*256 + threadIdx.x;
  if (idx >= 65536) return;
  int l = idx & 63, kk = (idx>>6)&7, m = (idx>>9)&7, us = (idx>>12)&7, d = (idx>>15)&1;
  int r = l & 15, g = r & 3, ut = r >> 2;
  int gcol = g*256 + us*32 + m*4 + ut;
  int k0 = kk*32 + (l>>4)*8;
  const float* wp = W + ((size_t)d*1024 + gcol)*256 + k0;
  u16 v[8];
  #pragma unroll
  for (int j=0;j<8;j++) v[j] = f2bf(wp[j]);
  *(uint4*)(out + (size_t)idx*8) = *(uint4*)v;
}

// decoder A-fragment prep (proven)
__global__ void k_prep_decA(const float* __restrict__ Wih0, const float* __restrict__ Whh0,
                            const float* __restrict__ Wih1, const float* __restrict__ Whh1,
                            u16* __restrict__ out){
  int idx = blockIdx.x*256 + threadIdx.x;
  if (idx >= 524288) return;
  int l = idx & 63, kk = (idx>>6)&31, cell = (idx>>11)&1, B = idx>>12;
  int r = l & 15;
  int ul = r >> 2, g = r & 3;
  int gcol = g*512 + B*4 + ul;
  int k0 = kk*32 + (l>>4)*8;
  u16 v[8];
  #pragma unroll
  for (int j=0;j<8;j++){
    int k = k0 + j;
    float wv;
    if (cell == 0) wv = (k < 512) ? Wih0[(size_t)gcol*640 + 128 + k] : Whh0[(size_t)gcol*512 + k - 512];
    else           wv = (k < 512) ? Wih1[(size_t)gcol*512 + k]       : Whh1[(size_t)gcol*512 + k - 512];
    v[j] = f2bf(wv);
  }
  *(uint4*)(out + (size_t)idx*8) = *(uint4*)v;
}

__global__ void k_prep_aTp(const float* __restrict__ aW1, u32* __restrict__ aTp){
  int idx = blockIdx.x*256 + threadIdx.x;
  if (idx >= 65536) return;
  int j2 = idx >> 8, c = idx & 255;
  aTp[idx] = packbf(aW1[(size_t)c*1024 + 2*j2], aW1[(size_t)c*1024 + 2*j2 + 1]);
}

__global__ void k_dinit(const float* __restrict__ eh0, const float* __restrict__ eh1,
                        u32* __restrict__ h0p, u32* __restrict__ h1p){
  int idx = blockIdx.x*256 + threadIdx.x;
  if (idx >= 8192) return;
  int b = idx >> 8, i = idx & 255;
  int dd = (2*i) >> 8, uu = (2*i) & 255;
  const float* p0 = eh0 + ((size_t)dd*32 + b)*256 + uu;
  const float* p1 = eh1 + ((size_t)dd*32 + b)*256 + uu;
  h0p[b*256 + i] = packbf(p0[0], p0[1]);
  h1p[b*256 + i] = packbf(p1[0], p1[1]);
}

// ---------------- bf16 MFMA GEMM (proven) ----------------
// flags: 1=relu, 2=remap (t*32+b)->(b*63+t), 4=remap (s*32+b)->(b*256+s)
__global__ __launch_bounds__(256) void k_mgemm(
    const float* __restrict__ A, const float* __restrict__ Bm,
    const float* __restrict__ bias, float* __restrict__ C,
    int M, int N, int K, int ldb, int boff, int flags){
  __shared__ u16 As[128*72];
  __shared__ u16 Bs[128*72];
  int tid = threadIdx.x;
  int m0 = blockIdx.x*128, n0 = blockIdx.y*128;
  int l = tid & 63, w = tid >> 6;
  int wr = w >> 1, wc = w & 1;
  int lr = l & 15, lk = (l >> 4) * 8;
  f32x4 acc[4][4];
  #pragma unroll
  for (int m=0;m<4;m++)
    #pragma unroll
    for (int n=0;n<4;n++) acc[m][n] = (f32x4){0.f,0.f,0.f,0.f};

  int r = tid >> 1, half = tid & 1;
  bool aval = (m0 + r) < M;
  const float* arow = A + (size_t)(m0 + r)*K + half*32;
  const float* brow = Bm + (size_t)(n0 + r)*ldb + boff + half*32;
  u16* asd = &As[r*72 + half*32];
  u16* bsd = &Bs[r*72 + half*32];

  for (int k0 = 0; k0 < K; k0 += 64){
    #pragma unroll
    for (int j = 0; j < 4; j++){
      float4 x = make_float4(0.f,0.f,0.f,0.f), y = x;
      if (aval){
        x = *(const float4*)(arow + k0 + j*8);
        y = *(const float4*)(arow + k0 + j*8 + 4);
      }
      asd[j*8+0]=f2bf(x.x); asd[j*8+1]=f2bf(x.y); asd[j*8+2]=f2bf(x.z); asd[j*8+3]=f2bf(x.w);
      asd[j*8+4]=f2bf(y.x); asd[j*8+5]=f2bf(y.y); asd[j*8+6]=f2bf(y.z); asd[j*8+7]=f2bf(y.w);
      float4 p = *(const float4*)(brow + k0 + j*8);
      float4 q = *(const float4*)(brow + k0 + j*8 + 4);
      bsd[j*8+0]=f2bf(p.x); bsd[j*8+1]=f2bf(p.y); bsd[j*8+2]=f2bf(p.z); bsd[j*8+3]=f2bf(p.w);
      bsd[j*8+4]=f2bf(q.x); bsd[j*8+5]=f2bf(q.y); bsd[j*8+6]=f2bf(q.z); bsd[j*8+7]=f2bf(q.w);
    }
    __syncthreads();
    #pragma unroll
    for (int kk = 0; kk < 2; kk++){
      short8v aF[4], bF[4];
      #pragma unroll
      for (int m = 0; m < 4; m++)
        aF[m] = *(short8v*)&As[(wr*64 + m*16 + lr)*72 + kk*32 + lk];
      #pragma unroll
      for (int n = 0; n < 4; n++)
        bF[n] = *(short8v*)&Bs[(wc*64 + n*16 + lr)*72 + kk*32 + lk];
      #pragma unroll
      for (int m = 0; m < 4; m++)
        #pragma unroll
        for (int n = 0; n < 4; n++)
          acc[m][n] = __builtin_amdgcn_mfma_f32_16x16x32_bf16(aF[m], bF[n], acc[m][n], 0, 0, 0);
    }
    __syncthreads();
  }

  #pragma unroll
  for (int m = 0; m < 4; m++){
    int gr0 = m0 + wr*64 + m*16 + (l >> 4)*4;
    #pragma unroll
    for (int n = 0; n < 4; n++){
      int gc = n0 + wc*64 + n*16 + (l & 15);
      float bv = bias[gc];
      #pragma unroll
      for (int j = 0; j < 4; j++){
        int gr = gr0 + j;
        if (gr >= M) continue;
        float v = acc[m][n][j] + bv;
        if (flags & 1) v = fmaxf(v, 0.f);
        if (flags & 2){
          int t = gr >> 5, b = gr & 31;
          C[((size_t)(b*63 + t))*(size_t)N + gc] = v;
        } else if (flags & 4){
          int s = gr >> 5, b = gr & 31;
          C[((size_t)(b*256 + s))*(size_t)N + gc] = v;
        } else {
          C[(size_t)gr*N + gc] = v;
        }
      }
    }
  }
}

// ---------------- persistent MFMA encoder scan v2 (proven, 32 blocks) ----------------
__global__ __launch_bounds__(256) void k_enc_scan(
    const float* __restrict__ Z, const u16* __restrict__ encA,
    float* __restrict__ y, u32* __restrict__ y1p,
    u32* __restrict__ hexp, float* __restrict__ hfin, float* __restrict__ cfin,
    unsigned* __restrict__ bars){
  extern __shared__ char smem[];
  char* ldsA = smem;            // 65536
  int blk = blockIdx.x, tid = threadIdx.x;
  int us = blk & 7, bh = (blk>>3)&1, d = blk>>4;
  int dom = d*2 + bh;
  unsigned* ctr = bars + dom*32;
  int w = tid >> 6, l = tid & 63;
  int lr = l & 15, lk = l >> 4;
  { const uint4* s = (const uint4*)(encA + (size_t)(d*8+us)*32768);
    uint4* dst = (uint4*)ldsA;
    for (int i = tid; i < 4096; i += 256) dst[i] = s[i]; }
  float c0 = 0.f, c1 = 0.f;
  int b_g = bh*16 + lr;
  int uc0 = us*32 + w*8 + lk, uc1 = uc0 + 4;
  u32* hx = hexp + dom*4096;
  __syncthreads();
  float za[4], zb[4];
  {
    int t0 = d ? 255 : 0;
    const float* zr = Z + ((size_t)t0*32 + b_g)*2048 + d*1024;
    #pragma unroll
    for (int j = 0; j < 4; j++){ za[j] = zr[j*256 + uc0]; zb[j] = zr[j*256 + uc1]; }
  }
  for (int i = 0; i < 256; i++){
    int t = d ? (255 - i) : i;
    int par_r = (i & 1) ^ 1;
    u64 bq[16];
    const u32* bs = hx + par_r*2048 + lr*128;
    #pragma unroll
    for (int kk = 0; kk < 8; kk++){
      bq[2*kk]   = ald64u(bs + kk*16 + lk*4);
      bq[2*kk+1] = ald64u(bs + kk*16 + lk*4 + 2);
    }
    f32x4 acc0 = (f32x4){0.f,0.f,0.f,0.f};
    f32x4 acc1 = (f32x4){0.f,0.f,0.f,0.f};
    #pragma unroll
    for (int kk = 0; kk < 8; kk++){
      short8v bF = mkfrag(bq[2*kk], bq[2*kk+1]);
      short8v a0 = *(const short8v*)(ldsA + (((w*2+0)*8 + kk)*64 + l)*16);
      short8v a1 = *(const short8v*)(ldsA + (((w*2+1)*8 + kk)*64 + l)*16);
      acc0 = __builtin_amdgcn_mfma_f32_16x16x32_bf16(a0, bF, acc0, 0, 0, 0);
      acc1 = __builtin_amdgcn_mfma_f32_16x16x32_bf16(a1, bF, acc1, 0, 0, 0);
    }
    float z0 = acc0[0]+za[0], z1 = acc0[1]+za[1], z2 = acc0[2]+za[2], z3 = acc0[3]+za[3];
    float cn = sigf(z1)*c0 + sigf(z0)*tanhf_fast(z2);
    float hn0 = sigf(z3)*tanhf_fast(cn); c0 = cn;
    z0 = acc1[0]+zb[0]; z1 = acc1[1]+zb[1]; z2 = acc1[2]+zb[2]; z3 = acc1[3]+zb[3];
    cn = sigf(z1)*c1 + sigf(z0)*tanhf_fast(z2);
    float hn1 = sigf(z3)*tanhf_fast(cn); c1 = cn;
    size_t yr = ((size_t)t*32 + b_g)*512 + d*256;
    y[yr + uc0] = hn0; y[yr + uc1] = hn1;
    float p0 = __shfl_xor(hn0, 16);
    float p1 = __shfl_xor(hn1, 16);
    if ((lk & 1) == 0){
      int base = us*16 + w*4 + (lk >> 1);
      u32 pk0 = packbf(hn0, p0), pk1 = packbf(hn1, p1);
      astu(hx + (i&1)*2048 + lr*128 + base,     pk0);
      astu(hx + (i&1)*2048 + lr*128 + base + 2, pk1);
      if (y1p){
        int gb = d*128 + base;
        y1p[((size_t)t*32 + b_g)*256 + gb]     = pk0;
        y1p[((size_t)t*32 + b_g)*256 + gb + 2] = pk1;
      }
    }
    if (i == 255){
      size_t fb = ((size_t)d*32 + b_g)*256;
      hfin[fb + uc0] = hn0; hfin[fb + uc1] = hn1;
      cfin[fb + uc0] = c0;  cfin[fb + uc1] = c1;
      break;
    }
    {
      int tn = d ? (254 - i) : (i + 1);
      const float* zr = Z + ((size_t)tn*32 + b_g)*2048 + d*1024;
      #pragma unroll
      for (int j = 0; j < 4; j++){ za[j] = zr[j*256 + uc0]; zb[j] = zr[j*256 + uc1]; }
    }
    icbar(ctr, (unsigned)(i+1)*8u);
  }
}

// ---------------- persistent MFMA decoder scan + fused output head ----------------
// Bid<128: scan (3 phases/step, distributed barrier, attention spread over ALL
// 128 blocks, 4 blocks per batch each owning 64 s-positions). Bid>=128: head (c-outer).
__global__ __launch_bounds__(256) void k_dec_scan(
    const u32* __restrict__ aTp, const float* __restrict__ eproj,
    const float* __restrict__ aW2, const u32* __restrict__ y1p,
    const float* __restrict__ zpre, const float* __restrict__ db1,
    const u16* __restrict__ decA,
    const float* __restrict__ e0c, const float* __restrict__ e1c,
    u32* __restrict__ h0p, u32* __restrict__ h1p,
    u32* __restrict__ ctxp, float* __restrict__ ctxS,
    float* __restrict__ H1all, unsigned* __restrict__ bars,
    const float* __restrict__ oW1, const float* __restrict__ ob1,
    const float* __restrict__ oW2, const float* __restrict__ ob2,
    u32* __restrict__ hidp, float* __restrict__ out){
  extern __shared__ char smem[];
  int Bid = blockIdx.x, tid = threadIdx.x;

  if (Bid < 128){
    // ================= scan block =================
    char* ldsA = smem;
    f32x4* pAc0 = (f32x4*)(smem + 65536);
    f32x4* pAc1 = (f32x4*)(smem + 65536 + 2048);
    f32x4* pB   = (f32x4*)(smem + 65536 + 4096);
    f32x4* pC   = (f32x4*)(smem + 65536 + 6144);
    float* h1s = (float*)(smem + 65536 + 8192);
    float* qs  = h1s + 512;
    float* w2s = qs + 256;
    float* es  = w2s + 256;   // 64 used
    int w = tid >> 6, l = tid & 63;
    int n_ = w & 1, kh = w >> 1;
    int lr = l & 15, lk = l >> 4;
    int idx = n_*64 + l;
    bool isRoot = (Bid == 127);
    { const uint4* s = (const uint4*)(decA + (size_t)Bid*32768);
      uint4* d4 = (uint4*)ldsA;
      for (int i = tid; i < 4096; i += 256) d4[i] = s[i]; }
    int attb = Bid >> 2, attp = Bid & 3;   // 4 blocks per batch, 64 s each
    w2s[tid] = aW2[tid];
    int u = Bid*4 + lk;
    int b_e = n_*16 + lr;
    float c0r=0.f, c1r=0.f, d0=0.f, d1=0.f, d2=0.f, d3=0.f;
    if (kh == 1){
      int dd = u >> 8, uu = u & 255;
      c0r = e0c[((size_t)dd*32 + b_e)*256 + uu];
      c1r = e1c[((size_t)dd*32 + b_e)*256 + uu];
      d0 = db1[u]; d1 = db1[512+u]; d2 = db1[1024+u]; d3 = db1[1536+u];
    }
    int brow_off = (n_*16 + lr)*256;
    __syncthreads();
    unsigned gen = 0;
    for (int t = 0; t < TD_; t++){
      int hp = t & 1;
      f32x4 rA0, rA1;
      float zp0=0.f, zp1=0.f, zp2=0.f, zp3=0.f;
      // ===== phase A: state-half partials + attention (all 128 blocks) =====
      {
        if (kh == 1){
          const float* zp = zpre + ((size_t)t*32 + b_e)*2048 + u;
          zp0 = zp[0]; zp1 = zp[512]; zp2 = zp[1024]; zp3 = zp[1536];
        }
        const u32* r0 = h0p + hp*8192 + brow_off;
        const u32* r1 = h1p + hp*8192 + brow_off;
        u64 qa[16], qb[16];
        #pragma unroll
        for (int k2 = 0; k2 < 8; k2++){
          int a = (kh*8 + k2)*16 + lk*4;
          qa[2*k2] = ald64u(r0 + a); qa[2*k2+1] = ald64u(r0 + a + 2);
        }
        #pragma unroll
        for (int k2 = 0; k2 < 8; k2++){
          int a = (kh*8 + k2)*16 + lk*4;
          qb[2*k2] = ald64u(r1 + a); qb[2*k2+1] = ald64u(r1 + a + 2);
        }
        f32x4 aA = (f32x4){0.f,0.f,0.f,0.f};
        f32x4 aB = (f32x4){0.f,0.f,0.f,0.f};
        #pragma unroll
        for (int k2 = 0; k2 < 8; k2++){
          short8v aF = *(const short8v*)(ldsA + (((16 + kh*8 + k2)*64) + l)*16);
          aA = __builtin_amdgcn_mfma_f32_16x16x32_bf16(aF, mkfrag(qa[2*k2], qa[2*k2+1]), aA, 0, 0, 0);
        }
        #pragma unroll
        for (int k2 = 0; k2 < 8; k2++){
          short8v aF = *(const short8v*)(ldsA + (((48 + kh*8 + k2)*64) + l)*16);
          aB = __builtin_amdgcn_mfma_f32_16x16x32_bf16(aF, mkfrag(qb[2*k2], qb[2*k2+1]), aB, 0, 0, 0);
        }
        if (kh == 0){ pAc0[idx] = aA; pAc1[idx] = aB; }
        else        { rA0 = aA; rA1 = aB; }
      }
      {
        int b = attb;
        u32 hv = aldu(h1p + hp*8192 + b*256 + tid);
        h1s[2*tid] = bflo(hv); h1s[2*tid+1] = bfhi(hv);
        __syncthreads();
        // q[c] full (duplicated across the 4 blocks of this batch)
        float q0=0.f,q1=0.f,q2=0.f,q3=0.f;
        for (int j2 = 0; j2 < 256; j2 += 4){
          u32 w0 = aTp[(j2+0)*256 + tid];
          u32 w1 = aTp[(j2+1)*256 + tid];
          u32 w2 = aTp[(j2+2)*256 + tid];
          u32 w3 = aTp[(j2+3)*256 + tid];
          q0 += bflo(w0)*h1s[2*j2]   + bfhi(w0)*h1s[2*j2+1];
          q1 += bflo(w1)*h1s[2*j2+2] + bfhi(w1)*h1s[2*j2+3];
          q2 += bflo(w2)*h1s[2*j2+4] + bfhi(w2)*h1s[2*j2+5];
          q3 += bflo(w3)*h1s[2*j2+6] + bfhi(w3)*h1s[2*j2+7];
        }
        qs[tid] = (q0+q1)+(q2+q3);
        __syncthreads();
        // scores for s-quarter attp (64 s): threads = 32 sl x 8 hc
        int sl = tid >> 3, hc = tid & 7;
        #pragma unroll
        for (int so = 0; so < 2; so++){
          int s = attp*64 + so*32 + sl;
          const float4* ep = (const float4*)(eproj + ((size_t)attb*256 + s)*256 + hc*32);
          const float4* q4 = (const float4*)(qs + hc*32);
          const float4* w4 = (const float4*)(w2s + hc*32);
          float acc = 0.f;
          #pragma unroll
          for (int k = 0; k < 8; k++){
            float4 e = ep[k], qq = q4[k], ww = w4[k];
            acc += tanhf_fast(e.x+qq.x)*ww.x + tanhf_fast(e.y+qq.y)*ww.y
                 + tanhf_fast(e.z+qq.z)*ww.z + tanhf_fast(e.w+qq.w)*ww.w;
          }
          acc += __shfl_xor(acc, 1);
          acc += __shfl_xor(acc, 2);
          acc += __shfl_xor(acc, 4);
          if (hc == 0) es[so*32 + sl] = __expf(acc);
        }
        __syncthreads();
        // raw exp-weighted ctx partial (this quarter) + S
        float a0 = 0.f, a1 = 0.f, b0 = 0.f, b1 = 0.f, S = 0.f;
        size_t ybase = ((size_t)(attp*64)*32 + b)*256 + tid;
        #pragma unroll 8
        for (int si = 0; si < 64; si += 2){
          float e0 = es[si], e1 = es[si+1];
          u32 v0 = y1p[ybase + (size_t)si*8192];
          u32 v1 = y1p[ybase + (size_t)(si+1)*8192];
          S += e0 + e1;
          a0 += e0*bflo(v0); a1 += e0*bfhi(v0);
          b0 += e1*bflo(v1); b1 += e1*bfhi(v1);
        }
        astu(ctxp + attp*8192 + b*256 + tid, packbf(a0+b0, a1+b1));
        if (tid == 0) astf(ctxS + attp*32 + b, S);
      }
      icbar3(bars, ++gen, isRoot);
      // ===== phase B: ctx (4 partials, kh-split pairs) + epilogue -> h0(t+1) =====
      {
        float S0=0.f,S1=0.f,S2=0.f,S3=0.f;
        if (kh == 1){
          S0 = aldf(ctxS + b_e);      S1 = aldf(ctxS + 32 + b_e);
          S2 = aldf(ctxS + 64 + b_e); S3 = aldf(ctxS + 96 + b_e);
        }
        const u32* rcA = ctxp + (kh*2+0)*8192 + brow_off;
        const u32* rcB = ctxp + (kh*2+1)*8192 + brow_off;
        f32x4 acc = (f32x4){0.f,0.f,0.f,0.f};
        acc = mma8(ldsA, 0, rcA, 0,   lk, l, acc);
        acc = mma8(ldsA, 8, rcA, 128, lk, l, acc);
        acc = mma8(ldsA, 0, rcB, 0,   lk, l, acc);
        acc = mma8(ldsA, 8, rcB, 128, lk, l, acc);
        if (kh == 0) pB[idx] = acc;
        __syncthreads();
        if (kh == 1){
          f32x4 oc = pB[idx];
          f32x4 oh = pAc0[idx];
          float sc = 1.0f / (S0 + S1 + S2 + S3);
          float z0 = (acc[0]+oc[0])*sc + oh[0] + rA0[0] + zp0;
          float z1 = (acc[1]+oc[1])*sc + oh[1] + rA0[1] + zp1;
          float z2 = (acc[2]+oc[2])*sc + oh[2] + rA0[2] + zp2;
          float z3 = (acc[3]+oc[3])*sc + oh[3] + rA0[3] + zp3;
          float cn = sigf(z1)*c0r + sigf(z0)*tanhf_fast(z2);
          float hn = sigf(z3)*tanhf_fast(cn);
          c0r = cn;
          float other = __shfl_xor(hn, 16);
          if ((lk & 1) == 0)
            astu(h0p + (1-hp)*8192 + b_e*256 + Bid*2 + (lk>>1), packbf(hn, other));
        }
      }
      icbar3(bars, ++gen, isRoot);
      // ===== phase C: h0-half of cell1 + epilogue -> h1(t+1) =====
      {
        const u32* rh = h0p + (1-hp)*8192 + brow_off;
        u64 qd[16];
        #pragma unroll
        for (int k2 = 0; k2 < 8; k2++){
          int a = (kh*8 + k2)*16 + lk*4;
          qd[2*k2] = ald64u(rh + a); qd[2*k2+1] = ald64u(rh + a + 2);
        }
        f32x4 acc = (f32x4){0.f,0.f,0.f,0.f};
        #pragma unroll
        for (int k2 = 0; k2 < 8; k2++){
          short8v aF = *(const short8v*)(ldsA + (((32 + kh*8 + k2)*64) + l)*16);
          acc = __builtin_amdgcn_mfma_f32_16x16x32_bf16(aF, mkfrag(qd[2*k2], qd[2*k2+1]), acc, 0, 0, 0);
        }
        if (kh == 0) pC[idx] = acc;
        __syncthreads();
        if (kh == 1){
          f32x4 oc = pC[idx];
          f32x4 oh = pAc1[idx];
          float z0 = acc[0] + oc[0] + oh[0] + rA1[0] + d0;
          float z1 = acc[1] + oc[1] + oh[1] + rA1[1] + d1;
          float z2 = acc[2] + oc[2] + oh[2] + rA1[2] + d2;
          float z3 = acc[3] + oc[3] + oh[3] + rA1[3] + d3;
          float cn = sigf(z1)*c1r + sigf(z0)*tanhf_fast(z2);
          float hn = sigf(z3)*tanhf_fast(cn);
          c1r = cn;
          astf(&H1all[((size_t)t*32 + b_e)*512 + u], hn);
          float other = __shfl_xor(hn, 16);
          if ((lk & 1) == 0)
            astu(h1p + (1-hp)*8192 + b_e*256 + Bid*2 + (lk>>1), packbf(hn, other));
        }
      }
      icbar3(bars, ++gen, isRoot);
    }
  } else {
    // ================= head block (c-outer, proven best) =================
    u16* As = (u16*)smem;
    u16* Bs = (u16*)(smem + 128*72*2);
    int hb = Bid - 128;
    int l = tid & 63, w = tid >> 6;
    int wr = w >> 1, wc = w & 1;
    int lr16 = l & 15, lk8 = (l >> 4) * 8;
    int r = tid >> 1, half = tid & 1;
    int cp = ((hb & 7) == 0 && (hb >> 3) < 16) ? (hb >> 3) : -1;
    for (int j = hb; j < 4000; j += 128){
      int c = j / 250, n = j % 250;
      if (cp >= 0 && cp <= c){
        unsigned need = (cp == 15) ? 189u : (unsigned)(12*cp + 12);
        if (tid == 0){
          while (aldu(bars + 1024) < need) __builtin_amdgcn_s_sleep(32);
        }
        __syncthreads();
        int rows = (cp == 15) ? 96 : 128;
        const float* Hc = H1all + (size_t)cp*128*512;
        for (int n0 = 0; n0 < 256; n0 += 128){
          f32x4 acc[4][4];
          #pragma unroll
          for (int m=0;m<4;m++)
            #pragma unroll
            for (int nn=0;nn<4;nn++) acc[m][nn] = (f32x4){0.f,0.f,0.f,0.f};
          for (int k0 = 0; k0 < 512; k0 += 64){
            u16* asd = &As[r*72 + half*32];
            if (r < rows){
              const u32* ap = (const u32*)(Hc + (size_t)r*512 + k0 + half*32);
              #pragma unroll
              for (int jj = 0; jj < 16; jj++){
                u64 v2 = ald64u(ap + 2*jj);
                asd[2*jj]   = f2bf(__uint_as_float((u32)v2));
                asd[2*jj+1] = f2bf(__uint_as_float((u32)(v2>>32)));
              }
            } else {
              #pragma unroll
              for (int jj = 0; jj < 16; jj++){ asd[2*jj]=0; asd[2*jj+1]=0; }
            }
            const float* brow = oW1 + (size_t)(n0 + r)*512 + k0 + half*32;
            u16* bsd = &Bs[r*72 + half*32];
            #pragma unroll
            for (int jj = 0; jj < 4; jj++){
              float4 p = *(const float4*)(brow + jj*8);
              float4 q = *(const float4*)(brow + jj*8 + 4);
              bsd[jj*8+0]=f2bf(p.x); bsd[jj*8+1]=f2bf(p.y); bsd[jj*8+2]=f2bf(p.z); bsd[jj*8+3]=f2bf(p.w);
              bsd[jj*8+4]=f2bf(q.x); bsd[jj*8+5]=f2bf(q.y); bsd[jj*8+6]=f2bf(q.z); bsd[jj*8+7]=f2bf(q.w);
            }
            __syncthreads();
            #pragma unroll
            for (int kk = 0; kk < 2; kk++){
              short8v aF[4], bF[4];
              #pragma unroll
              for (int m = 0; m < 4; m++)
                aF[m] = *(short8v*)&As[(wr*64 + m*16 + lr16)*72 + kk*32 + lk8];
              #pragma unroll
              for (int nn = 0; nn < 4; nn++)
                bF[nn] = *(short8v*)&Bs[(wc*64 + nn*16 + lr16)*72 + kk*32 + lk8];
              #pragma unroll
              for (int m = 0; m < 4; m++)
                #pragma unroll
                for (int nn = 0; nn < 4; nn++)
                  acc[m][nn] = __builtin_amdgcn_mfma_f32_16x16x32_bf16(aF[m], bF[nn], acc[m][nn], 0, 0, 0);
            }
            __syncthreads();
          }
          #pragma unroll
          for (int m = 0; m < 4; m++){
            int gr0 = wr*64 + m*16 + (l >> 4)*4;
            #pragma unroll
            for (int nn = 0; nn < 4; nn++){
              int gc = n0 + wc*64 + nn*16 + (l & 15);
              float bv = ob1[gc];
              #pragma unroll
              for (int j4 = 0; j4 < 4; j4++){
                int gr = gr0 + j4;
                float v = fmaxf(acc[m][nn][j4] + bv, 0.f);
                float o = __shfl_xor(v, 1);
                if ((l & 1) == 0 && gr < rows)
                  astu(hidp + (size_t)cp*16384 + gr*128 + (gc>>1), packbf(v, o));
              }
            }
          }
        }
        vdrain();
        __syncthreads();
        if (tid == 0) astu(bars + 1088 + cp, 1u);
        cp = -1;
      }
      if (tid == 0){
        while (aldu(bars + 1088 + c) == 0) __builtin_amdgcn_s_sleep(16);
      }
      __syncthreads();
      int rows = (c == 15) ? 96 : 128;
      int n0g = n * 128;
      f32x4 acc[4][4];
      #pragma unroll
      for (int m=0;m<4;m++)
        #pragma unroll
        for (int nn=0;nn<4;nn++) acc[m][nn] = (f32x4){0.f,0.f,0.f,0.f};
      const u32* hc = hidp + (size_t)c*16384;
      for (int k0 = 0; k0 < 256; k0 += 64){
        u32* asd32 = (u32*)&As[r*72 + half*32];
        if (r < rows){
          const u32* ap = hc + r*128 + (k0>>1) + half*16;
          #pragma unroll
          for (int jj = 0; jj < 8; jj++){
            u64 v2 = ald64u(ap + 2*jj);
            asd32[2*jj] = (u32)v2; asd32[2*jj+1] = (u32)(v2>>32);
          }
        } else {
          #pragma unroll
          for (int jj = 0; jj < 8; jj++){ asd32[2*jj]=0; asd32[2*jj+1]=0; }
        }
        const float* brow = oW2 + (size_t)(n0g + r)*256 + k0 + half*32;
        u16* bsd = &Bs[r*72 + half*32];
        #pragma unroll
        for (int jj = 0; jj < 4; jj++){
          float4 p = *(const float4*)(brow + jj*8);
          float4 q = *(const float4*)(brow + jj*8 + 4);
          bsd[jj*8+0]=f2bf(p.x); bsd[jj*8+1]=f2bf(p.y); bsd[jj*8+2]=f2bf(p.z); bsd[jj*8+3]=f2bf(p.w);
          bsd[jj*8+4]=f2bf(q.x); bsd[jj*8+5]=f2bf(q.y); bsd[jj*8+6]=f2bf(q.z); bsd[jj*8+7]=f2bf(q.w);
        }
        __syncthreads();
        #pragma unroll
        for (int kk = 0; kk < 2; kk++){
          short8v aF[4], bF[4];
          #pragma unroll
          for (int m = 0; m < 4; m++)
            aF[m] = *(short8v*)&As[(wr*64 + m*16 + lr16)*72 + kk*32 + lk8];
          #pragma unroll
          for (int nn = 0; nn < 4; nn++)
            bF[nn] = *(short8v*)&Bs[(wc*64 + nn*16 + lr16)*72 + kk*32 + lk8];
          #pragma unroll
          for (int m = 0; m < 4; m++)
            #pragma unroll
            for (int nn = 0; nn < 4; nn++)
              acc[m][nn] = __builtin_amdgcn_mfma_f32_16x16x32_bf16(aF[m], bF[nn], acc[m][nn], 0, 0, 0);
        }
        __syncthreads();
      }
      #pragma unroll
      for (int m = 0; m < 4; m++){
        int gr0 = wr*64 + m*16 + (l >> 4)*4;
        #pragma unroll
        for (int nn = 0; nn < 4; nn++){
          int gc = n0g + wc*64 + nn*16 + (l & 15);
          float bv = ob2[gc];
          #pragma unroll
          for (int j4 = 0; j4 < 4; j4++){
            int gr = gr0 + j4;
            if (gr < rows){
              int gt = c*4 + (gr >> 5), b = gr & 31;
              out[((size_t)(b*63 + gt))*(size_t)VV_ + gc] = acc[m][nn][j4] + bv;
            }
          }
        }
      }
    }
  }
}

// ---------------- host launch ----------------
extern "C" void kernel_launch(void* const* d_in, const int* in_sizes, int n_in,
                              void* d_out, int out_size, void* d_ws, size_t ws_size,
                              hipStream_t stream){
  (void)in_sizes; (void)n_in; (void)out_size;
  const int*   src   = (const int*)d_in[0];
  const int*   tgt   = (const int*)d_in[1];
  const float* emb   = (const float*)d_in[2];
  const float* eWih0 = (const float*)d_in[3];
  const float* eWhh0 = (const float*)d_in[4];
  const float* eb0   = (const float*)d_in[5];
  const float* eWih1 = (const float*)d_in[6];
  const float* eWhh1 = (const float*)d_in[7];
  const float* eb1   = (const float*)d_in[8];
  const float* dWih0 = (const float*)d_in[9];
  const float* dWhh0 = (const float*)d_in[10];
  const float* db0   = (const float*)d_in[11];
  const float* dWih1 = (const float*)d_in[12];
  const float* dWhh1 = (const float*)d_in[13];
  const float* db1   = (const float*)d_in[14];
  const float* aW1   = (const float*)d_in[15];
  const float* ab1   = (const float*)d_in[16];
  const float* aW2   = (const float*)d_in[17];
  const float* oW1   = (const float*)d_in[19];
  const float* ob1   = (const float*)d_in[20];
  const float* oW2   = (const float*)d_in[21];
  const float* ob2   = (const float*)d_in[22];

  float* F = (float*)d_out;
  float* W = (float*)d_ws;
  bool fused = (ws_size >= (size_t)48*1024*1024);

  float* Z     = F + OFF_Z;
  float* y0    = F + OFF_Y0;
  float* y1    = F + OFF_Y1;
  float* srcE  = F + OFF_SRCE;
  float* tgtE  = F + OFF_TGTE;
  u16*   encA0 = (u16*)(F + OFF_ENCA0);
  u16*   encA1 = (u16*)(F + OFF_ENCA1);
  float* e0h   = F + OFF_E0H;
  float* e0c   = F + OFF_E0C;
  float* e1h   = F + OFF_E1H;
  float* e1c   = F + OFF_E1C;
  u32*   hexA  = (u32*)(F + OFF_HEXA);
  u32*   hexB  = (u32*)(F + OFF_HEXB);
  unsigned* bars = (unsigned*)(F + OFF_BARS);

  float* zpre  = fused ? (W + W_ZPRE)  : (F + OFF_ZPRE);
  float* H1    = fused ? (W + W_H1ALL) : (F + OFF_H1ALL);
  float* eproj = fused ? (W + W_EPROJ) : (F + OFF_EPROJ);
  u16*   decA  = fused ? (u16*)(W + W_DECA) : (u16*)(F + OFF_DECA);
  u32*   aTp   = fused ? (u32*)(W + W_ATP)  : (u32*)(F + OFF_ATP);
  u32*   h0p   = fused ? (u32*)(W + W_H0P)  : (u32*)(F + OFF_H0P);
  u32*   h1p   = fused ? (u32*)(W + W_H1P)  : (u32*)(F + OFF_H1P);
  u32*   ctxp  = fused ? (u32*)(W + W_CTXP) : (u32*)(F + OFF_CTXP);
  float* ctxS  = fused ? (W + W_CTXS)       : (F + OFF_CTXS);
  u32*   y1p   = fused ? (u32*)(W + W_Y1P)  : (u32*)(F + OFF_Y1P);
  unsigned* dbars = fused ? (unsigned*)(W + W_DBAR) : (bars + 256);
  u32*   hidp  = fused ? (u32*)(W + W_HIDP) : (u32*)d_ws;
  float* hid   = (float*)d_ws;

  hipFuncSetAttribute((const void*)k_enc_scan, hipFuncAttributeMaxDynamicSharedMemorySize, 65536);
  hipFuncSetAttribute((const void*)k_dec_scan, hipFuncAttributeMaxDynamicSharedMemorySize, 78336);

  // zero hexp + enc/dec barrier regions
  k_zero<<<135,256,0,stream>>>(F + OFF_HEXA, 34304);
  if (fused) k_zero<<<8,256,0,stream>>>(W + W_DBAR, 2048);
  k_gather<<<((8192+2016)*32+255)/256,256,0,stream>>>(src, tgt, emb, srcE, tgtE);
  k_prep_encA<<<256,256,0,stream>>>(eWhh0, encA0);
  k_prep_encA<<<256,256,0,stream>>>(eWhh1, encA1);
  k_prep_decA<<<2048,256,0,stream>>>(dWih0, dWhh0, dWih1, dWhh1, decA);
  k_prep_aTp<<<256,256,0,stream>>>(aW1, aTp);

  // encoder layer0
  k_mgemm<<<dim3(64,16),256,0,stream>>>(srcE, eWih0, eb0, Z, 8192,2048,128, 128,0,0);
  k_enc_scan<<<32,256,65536,stream>>>(Z, encA0, y0, (u32*)nullptr, hexA, e0h, e0c, bars);
  // encoder layer1 (emits packed y1p)
  k_mgemm<<<dim3(64,16),256,0,stream>>>(y0, eWih1, eb1, Z, 8192,2048,512, 512,0,0);
  k_enc_scan<<<32,256,65536,stream>>>(Z, encA1, y1, y1p, hexB, e1h, e1c, bars + 128);

  // projections + decoder init
  k_mgemm<<<dim3(64,2),256,0,stream>>>(y1, aW1, ab1, eproj, 8192,256,512, 1024,512,4);
  k_mgemm<<<dim3(16,16),256,0,stream>>>(tgtE, dWih0, db0, zpre, 2016,2048,128, 640,0,0);
  k_dinit<<<32,256,0,stream>>>(e0h, e1h, h0p, h1p);

  // decoder (+ fused head if ws is large enough)
  int decBlocks = fused ? 256 : 128;
  k_dec_scan<<<decBlocks,256,78336,stream>>>(aTp, eproj, aW2, y1p, zpre, db1, decA,
                                             e0c, e1c, h0p, h1p, ctxp, ctxS, H1, dbars,
                                             oW1, ob1, oW2, ob2, hidp, F);

  if (!fused){
    k_mgemm<<<dim3(16,2),256,0,stream>>>(H1, oW1, ob1, hid, 2016,256,512, 512,0,1);
    k_mgemm<<<dim3(16,250),256,0,stream>>>(hid, oW2, ob2, F, 2016,32000,256, 256,0,2);
  }
}

// Round 16
// 4291.484 us; speedup vs baseline: 1.0420x; 1.0420x over previous
//
#include <hip/hip_runtime.h>

// ---------------- problem constants ----------------
#define BB_ 32
#define SS_ 256
#define TD_ 63
#define EE_ 128
#define VV_ 32000

typedef unsigned short u16;
typedef unsigned int u32;
typedef unsigned long long u64;
typedef __attribute__((ext_vector_type(8))) short short8v;
typedef __attribute__((ext_vector_type(4))) float f32x4;

__device__ __forceinline__ float sigf(float x){ return 1.0f/(1.0f+__expf(-x)); }
__device__ __forceinline__ float tanhf_fast(float x){ return 1.0f - 2.0f/(__expf(2.0f*x)+1.0f); }
__device__ __forceinline__ u16 f2bf(float f){
  unsigned u = __float_as_uint(f);
  u += 0x7fff + ((u >> 16) & 1);
  return (u16)(u >> 16);
}
__device__ __forceinline__ u32 packbf(float a, float b){
  return (u32)f2bf(a) | ((u32)f2bf(b) << 16);
}
__device__ __forceinline__ float bflo(u32 v){ return __uint_as_float(v << 16); }
__device__ __forceinline__ float bfhi(u32 v){ return __uint_as_float(v & 0xffff0000u); }

// ---- coherent (agent-scope) payload accessors ----
__device__ __forceinline__ u32 aldu(const u32* p){
  return __hip_atomic_load(p, __ATOMIC_RELAXED, __HIP_MEMORY_SCOPE_AGENT);
}
__device__ __forceinline__ u64 ald64u(const u32* p){
  return __hip_atomic_load((const u64*)p, __ATOMIC_RELAXED, __HIP_MEMORY_SCOPE_AGENT);
}
__device__ __forceinline__ void astu(u32* p, u32 v){
  __hip_atomic_store(p, v, __ATOMIC_RELAXED, __HIP_MEMORY_SCOPE_AGENT);
}
__device__ __forceinline__ float aldf(const float* p){
  return __hip_atomic_load(p, __ATOMIC_RELAXED, __HIP_MEMORY_SCOPE_AGENT);
}
__device__ __forceinline__ void astf(float* p, float v){
  __hip_atomic_store(p, v, __ATOMIC_RELAXED, __HIP_MEMORY_SCOPE_AGENT);
}
__device__ __forceinline__ void vdrain(){ asm volatile("s_waitcnt vmcnt(0)" ::: "memory"); }

__device__ __forceinline__ short8v mkfrag(u64 a, u64 b){
  union { u32 u[4]; short8v v; } c;
  c.u[0] = (u32)a; c.u[1] = (u32)(a >> 32);
  c.u[2] = (u32)b; c.u[3] = (u32)(b >> 32);
  return c.v;
}

// 8-kk MFMA batch: A frags from LDS starting at kk=akk0; B direct from packed global
__device__ __forceinline__ f32x4 mma8(const char* ldsA, int akk0, const u32* brow,
                                      int boff, int lk, int l, f32x4 acc){
  u64 bq[16];
  #pragma unroll
  for (int k2 = 0; k2 < 8; k2++){
    int a = boff + k2*16 + lk*4;
    bq[2*k2]   = ald64u(brow + a);
    bq[2*k2+1] = ald64u(brow + a + 2);
  }
  #pragma unroll
  for (int k2 = 0; k2 < 8; k2++){
    short8v aF = *(const short8v*)(ldsA + (((akk0 + k2)*64) + l)*16);
    acc = __builtin_amdgcn_mfma_f32_16x16x32_bf16(aF, mkfrag(bq[2*k2], bq[2*k2+1]), acc, 0, 0, 0);
  }
  return acc;
}

// ---------------- d_out scratch layout (float offsets) ----------------
#define OFF_Z        0u
#define OFF_Y0       16777216u
#define OFF_Y1       20971520u
#define OFF_ZPRE     25165824u
#define OFF_H1ALL    29294592u
#define OFF_SRCE     30326784u
#define OFF_TGTE     31375360u
#define OFF_EPROJ    31633408u
#define OFF_ENCA0    33730560u
#define OFF_ENCA1    33992704u
#define OFF_DECA     34254848u
#define OFF_ATP      36352000u
#define OFF_E0H      36417536u
#define OFF_E0C      36433920u
#define OFF_E1H      36450304u
#define OFF_E1C      36466688u
#define OFF_H0P      36483072u
#define OFF_H1P      36499456u
#define OFF_CTXP     36515840u   // 4 partials x 8192 u32 (32768 fl)
#define OFF_CTXS     36548608u   // 128 f32
#define OFF_Y1P      36548736u   // 2097152 fl
#define OFF_HEXA     38645888u
#define OFF_HEXB     38662272u
#define OFF_BARS     38678656u

// ---------------- ws scratch layout (float offsets, fused path) ----------------
#define W_EPROJ   0u
#define W_ZPRE    2097152u
#define W_Y1P     6225920u
#define W_DECA    8323072u
#define W_ATP     10420224u
#define W_H0P     10485760u
#define W_H1P     10502144u
#define W_CTXP    10518528u      // 32768 fl
#define W_CTXS    10551296u      // 128 fl
#define W_H1ALL   10551424u
#define W_HIDP    11583616u
#define W_DBAR    11845760u
#define W_TOTAL   11847808u      // ~47.4 MB

// ---------------- fence-free barriers ----------------
__device__ __forceinline__ void icbar(unsigned* ctr, unsigned target){
  vdrain();
  __syncthreads();
  if (threadIdx.x == 0){
    __hip_atomic_fetch_add(ctr, 1u, __ATOMIC_RELAXED, __HIP_MEMORY_SCOPE_AGENT);
    while (__hip_atomic_load(ctr, __ATOMIC_RELAXED, __HIP_MEMORY_SCOPE_AGENT) < target)
      __builtin_amdgcn_s_sleep(1);
  }
  __syncthreads();
  asm volatile("" ::: "memory");
}

// decoder tree-release barrier (PROVEN best, R14): arrive on 16 group counters;
// root block's wave0 polls all 16 with 16 lanes, then stores 16 release words;
// 8 blocks poll each release line. + progress word for head blocks.
__device__ __forceinline__ void icbar3(unsigned* db, unsigned gen, bool isRoot){
  vdrain();
  __syncthreads();
  int tid = threadIdx.x;
  unsigned g = (unsigned)blockIdx.x & 15u;
  if (tid == 0)
    __hip_atomic_fetch_add(&db[g*32], 1u, __ATOMIC_RELAXED, __HIP_MEMORY_SCOPE_AGENT);
  if (isRoot){
    if (tid < 64){
      unsigned tgt = gen * 8u;
      for (;;){
        unsigned a = (tid < 16)
          ? __hip_atomic_load(&db[(unsigned)tid*32], __ATOMIC_RELAXED, __HIP_MEMORY_SCOPE_AGENT)
          : tgt;
        if (__all(a >= tgt)) break;
        __builtin_amdgcn_s_sleep(1);
      }
      if (tid < 16)
        __hip_atomic_store(&db[512 + (unsigned)tid*32], gen, __ATOMIC_RELAXED, __HIP_MEMORY_SCOPE_AGENT);
      if (tid == 16)
        __hip_atomic_store(&db[1024], gen, __ATOMIC_RELAXED, __HIP_MEMORY_SCOPE_AGENT);
    }
  } else {
    if (tid == 0){
      while (__hip_atomic_load(&db[512 + g*32], __ATOMIC_RELAXED, __HIP_MEMORY_SCOPE_AGENT) < gen)
        __builtin_amdgcn_s_sleep(1);
    }
  }
  __syncthreads();
  asm volatile("" ::: "memory");
}

// ---------------- utility kernels ----------------
__global__ void k_zero(float* __restrict__ p, int n){
  int i = blockIdx.x*256 + threadIdx.x;
  if (i < n) p[i] = 0.f;
}

__global__ void k_gather(const int* __restrict__ src, const int* __restrict__ tgt,
                         const float* __restrict__ emb,
                         float* __restrict__ src_e, float* __restrict__ tgt_e){
  int idx = blockIdx.x*256 + threadIdx.x;
  const int total = (8192 + 2016) * 32;
  if (idx >= total) return;
  int row = idx >> 5, j = idx & 31;
  int tok; float* dst;
  if (row < 8192){
    int s = row >> 5, b = row & 31;
    tok = src[b*SS_ + s];
    dst = src_e + (size_t)row*EE_;
  } else {
    int r2 = row - 8192;
    int t = r2 >> 5, b = r2 & 31;
    tok = tgt[b*64 + t];
    dst = tgt_e + (size_t)r2*EE_;
  }
  float4 v = *(const float4*)(emb + (size_t)tok*EE_ + j*4);
  *(float4*)(dst + j*4) = v;
}

// encoder v2 A-fragment prep (proven)
__global__ void k_prep_encA(const float* __restrict__ W, u16* __restrict__ out){
  int idx = blockIdx.x*256 + threadIdx.x;
  if (idx >= 65536) return;
  int l = idx & 63, kk = (idx>>6)&7, m = (idx>>9)&7, us = (idx>>12)&7, d = (idx>>15)&1;
  int r = l & 15, g = r & 3, ut = r >> 2;
  int gcol = g*256 + us*32 + m*4 + ut;
  int k0 = kk*32 + (l>>4)*8;
  const float* wp = W + ((size_t)d*1024 + gcol)*256 + k0;
  u16 v[8];
  #pragma unroll
  for (int j=0;j<8;j++) v[j] = f2bf(wp[j]);
  *(uint4*)(out + (size_t)idx*8) = *(uint4*)v;
}

// decoder A-fragment prep (proven)
__global__ void k_prep_decA(const float* __restrict__ Wih0, const float* __restrict__ Whh0,
                            const float* __restrict__ Wih1, const float* __restrict__ Whh1,
                            u16* __restrict__ out){
  int idx = blockIdx.x*256 + threadIdx.x;
  if (idx >= 524288) return;
  int l = idx & 63, kk = (idx>>6)&31, cell = (idx>>11)&1, B = idx>>12;
  int r = l & 15;
  int ul = r >> 2, g = r & 3;
  int gcol = g*512 + B*4 + ul;
  int k0 = kk*32 + (l>>4)*8;
  u16 v[8];
  #pragma unroll
  for (int j=0;j<8;j++){
    int k = k0 + j;
    float wv;
    if (cell == 0) wv = (k < 512) ? Wih0[(size_t)gcol*640 + 128 + k] : Whh0[(size_t)gcol*512 + k - 512];
    else           wv = (k < 512) ? Wih1[(size_t)gcol*512 + k]       : Whh1[(size_t)gcol*512 + k - 512];
    v[j] = f2bf(wv);
  }
  *(uint4*)(out + (size_t)idx*8) = *(uint4*)v;
}

__global__ void k_prep_aTp(const float* __restrict__ aW1, u32* __restrict__ aTp){
  int idx = blockIdx.x*256 + threadIdx.x;
  if (idx >= 65536) return;
  int j2 = idx >> 8, c = idx & 255;
  aTp[idx] = packbf(aW1[(size_t)c*1024 + 2*j2], aW1[(size_t)c*1024 + 2*j2 + 1]);
}

__global__ void k_dinit(const float* __restrict__ eh0, const float* __restrict__ eh1,
                        u32* __restrict__ h0p, u32* __restrict__ h1p){
  int idx = blockIdx.x*256 + threadIdx.x;
  if (idx >= 8192) return;
  int b = idx >> 8, i = idx & 255;
  int dd = (2*i) >> 8, uu = (2*i) & 255;
  const float* p0 = eh0 + ((size_t)dd*32 + b)*256 + uu;
  const float* p1 = eh1 + ((size_t)dd*32 + b)*256 + uu;
  h0p[b*256 + i] = packbf(p0[0], p0[1]);
  h1p[b*256 + i] = packbf(p1[0], p1[1]);
}

// ---------------- bf16 MFMA GEMM (proven) ----------------
// flags: 1=relu, 2=remap (t*32+b)->(b*63+t), 4=remap (s*32+b)->(b*256+s)
__global__ __launch_bounds__(256) void k_mgemm(
    const float* __restrict__ A, const float* __restrict__ Bm,
    const float* __restrict__ bias, float* __restrict__ C,
    int M, int N, int K, int ldb, int boff, int flags){
  __shared__ u16 As[128*72];
  __shared__ u16 Bs[128*72];
  int tid = threadIdx.x;
  int m0 = blockIdx.x*128, n0 = blockIdx.y*128;
  int l = tid & 63, w = tid >> 6;
  int wr = w >> 1, wc = w & 1;
  int lr = l & 15, lk = (l >> 4) * 8;
  f32x4 acc[4][4];
  #pragma unroll
  for (int m=0;m<4;m++)
    #pragma unroll
    for (int n=0;n<4;n++) acc[m][n] = (f32x4){0.f,0.f,0.f,0.f};

  int r = tid >> 1, half = tid & 1;
  bool aval = (m0 + r) < M;
  const float* arow = A + (size_t)(m0 + r)*K + half*32;
  const float* brow = Bm + (size_t)(n0 + r)*ldb + boff + half*32;
  u16* asd = &As[r*72 + half*32];
  u16* bsd = &Bs[r*72 + half*32];

  for (int k0 = 0; k0 < K; k0 += 64){
    #pragma unroll
    for (int j = 0; j < 4; j++){
      float4 x = make_float4(0.f,0.f,0.f,0.f), y = x;
      if (aval){
        x = *(const float4*)(arow + k0 + j*8);
        y = *(const float4*)(arow + k0 + j*8 + 4);
      }
      asd[j*8+0]=f2bf(x.x); asd[j*8+1]=f2bf(x.y); asd[j*8+2]=f2bf(x.z); asd[j*8+3]=f2bf(x.w);
      asd[j*8+4]=f2bf(y.x); asd[j*8+5]=f2bf(y.y); asd[j*8+6]=f2bf(y.z); asd[j*8+7]=f2bf(y.w);
      float4 p = *(const float4*)(brow + k0 + j*8);
      float4 q = *(const float4*)(brow + k0 + j*8 + 4);
      bsd[j*8+0]=f2bf(p.x); bsd[j*8+1]=f2bf(p.y); bsd[j*8+2]=f2bf(p.z); bsd[j*8+3]=f2bf(p.w);
      bsd[j*8+4]=f2bf(q.x); bsd[j*8+5]=f2bf(q.y); bsd[j*8+6]=f2bf(q.z); bsd[j*8+7]=f2bf(q.w);
    }
    __syncthreads();
    #pragma unroll
    for (int kk = 0; kk < 2; kk++){
      short8v aF[4], bF[4];
      #pragma unroll
      for (int m = 0; m < 4; m++)
        aF[m] = *(short8v*)&As[(wr*64 + m*16 + lr)*72 + kk*32 + lk];
      #pragma unroll
      for (int n = 0; n < 4; n++)
        bF[n] = *(short8v*)&Bs[(wc*64 + n*16 + lr)*72 + kk*32 + lk];
      #pragma unroll
      for (int m = 0; m < 4; m++)
        #pragma unroll
        for (int n = 0; n < 4; n++)
          acc[m][n] = __builtin_amdgcn_mfma_f32_16x16x32_bf16(aF[m], bF[n], acc[m][n], 0, 0, 0);
    }
    __syncthreads();
  }

  #pragma unroll
  for (int m = 0; m < 4; m++){
    int gr0 = m0 + wr*64 + m*16 + (l >> 4)*4;
    #pragma unroll
    for (int n = 0; n < 4; n++){
      int gc = n0 + wc*64 + n*16 + (l & 15);
      float bv = bias[gc];
      #pragma unroll
      for (int j = 0; j < 4; j++){
        int gr = gr0 + j;
        if (gr >= M) continue;
        float v = acc[m][n][j] + bv;
        if (flags & 1) v = fmaxf(v, 0.f);
        if (flags & 2){
          int t = gr >> 5, b = gr & 31;
          C[((size_t)(b*63 + t))*(size_t)N + gc] = v;
        } else if (flags & 4){
          int s = gr >> 5, b = gr & 31;
          C[((size_t)(b*256 + s))*(size_t)N + gc] = v;
        } else {
          C[(size_t)gr*N + gc] = v;
        }
      }
    }
  }
}

// ---------------- persistent MFMA encoder scan v2 (proven, 32 blocks) ----------------
__global__ __launch_bounds__(256) void k_enc_scan(
    const float* __restrict__ Z, const u16* __restrict__ encA,
    float* __restrict__ y, u32* __restrict__ y1p,
    u32* __restrict__ hexp, float* __restrict__ hfin, float* __restrict__ cfin,
    unsigned* __restrict__ bars){
  extern __shared__ char smem[];
  char* ldsA = smem;            // 65536
  int blk = blockIdx.x, tid = threadIdx.x;
  int us = blk & 7, bh = (blk>>3)&1, d = blk>>4;
  int dom = d*2 + bh;
  unsigned* ctr = bars + dom*32;
  int w = tid >> 6, l = tid & 63;
  int lr = l & 15, lk = l >> 4;
  { const uint4* s = (const uint4*)(encA + (size_t)(d*8+us)*32768);
    uint4* dst = (uint4*)ldsA;
    for (int i = tid; i < 4096; i += 256) dst[i] = s[i]; }
  float c0 = 0.f, c1 = 0.f;
  int b_g = bh*16 + lr;
  int uc0 = us*32 + w*8 + lk, uc1 = uc0 + 4;
  u32* hx = hexp + dom*4096;
  __syncthreads();
  float za[4], zb[4];
  {
    int t0 = d ? 255 : 0;
    const float* zr = Z + ((size_t)t0*32 + b_g)*2048 + d*1024;
    #pragma unroll
    for (int j = 0; j < 4; j++){ za[j] = zr[j*256 + uc0]; zb[j] = zr[j*256 + uc1]; }
  }
  for (int i = 0; i < 256; i++){
    int t = d ? (255 - i) : i;
    int par_r = (i & 1) ^ 1;
    u64 bq[16];
    const u32* bs = hx + par_r*2048 + lr*128;
    #pragma unroll
    for (int kk = 0; kk < 8; kk++){
      bq[2*kk]   = ald64u(bs + kk*16 + lk*4);
      bq[2*kk+1] = ald64u(bs + kk*16 + lk*4 + 2);
    }
    f32x4 acc0 = (f32x4){0.f,0.f,0.f,0.f};
    f32x4 acc1 = (f32x4){0.f,0.f,0.f,0.f};
    #pragma unroll
    for (int kk = 0; kk < 8; kk++){
      short8v bF = mkfrag(bq[2*kk], bq[2*kk+1]);
      short8v a0 = *(const short8v*)(ldsA + (((w*2+0)*8 + kk)*64 + l)*16);
      short8v a1 = *(const short8v*)(ldsA + (((w*2+1)*8 + kk)*64 + l)*16);
      acc0 = __builtin_amdgcn_mfma_f32_16x16x32_bf16(a0, bF, acc0, 0, 0, 0);
      acc1 = __builtin_amdgcn_mfma_f32_16x16x32_bf16(a1, bF, acc1, 0, 0, 0);
    }
    float z0 = acc0[0]+za[0], z1 = acc0[1]+za[1], z2 = acc0[2]+za[2], z3 = acc0[3]+za[3];
    float cn = sigf(z1)*c0 + sigf(z0)*tanhf_fast(z2);
    float hn0 = sigf(z3)*tanhf_fast(cn); c0 = cn;
    z0 = acc1[0]+zb[0]; z1 = acc1[1]+zb[1]; z2 = acc1[2]+zb[2]; z3 = acc1[3]+zb[3];
    cn = sigf(z1)*c1 + sigf(z0)*tanhf_fast(z2);
    float hn1 = sigf(z3)*tanhf_fast(cn); c1 = cn;
    size_t yr = ((size_t)t*32 + b_g)*512 + d*256;
    y[yr + uc0] = hn0; y[yr + uc1] = hn1;
    float p0 = __shfl_xor(hn0, 16);
    float p1 = __shfl_xor(hn1, 16);
    if ((lk & 1) == 0){
      int base = us*16 + w*4 + (lk >> 1);
      u32 pk0 = packbf(hn0, p0), pk1 = packbf(hn1, p1);
      astu(hx + (i&1)*2048 + lr*128 + base,     pk0);
      astu(hx + (i&1)*2048 + lr*128 + base + 2, pk1);
      if (y1p){
        int gb = d*128 + base;
        y1p[((size_t)t*32 + b_g)*256 + gb]     = pk0;
        y1p[((size_t)t*32 + b_g)*256 + gb + 2] = pk1;
      }
    }
    if (i == 255){
      size_t fb = ((size_t)d*32 + b_g)*256;
      hfin[fb + uc0] = hn0; hfin[fb + uc1] = hn1;
      cfin[fb + uc0] = c0;  cfin[fb + uc1] = c1;
      break;
    }
    {
      int tn = d ? (254 - i) : (i + 1);
      const float* zr = Z + ((size_t)tn*32 + b_g)*2048 + d*1024;
      #pragma unroll
      for (int j = 0; j < 4; j++){ za[j] = zr[j*256 + uc0]; zb[j] = zr[j*256 + uc1]; }
    }
    icbar(ctr, (unsigned)(i+1)*8u);
  }
}

// ---------------- persistent MFMA decoder scan + fused output head ----------------
// Bid<128: scan (3 phases/step, tree barrier, attention spread over ALL 128 blocks,
// 4 blocks/batch x 64 s; h0 fragment carried in regs C->A). Bid>=128: head (c-outer).
__global__ __launch_bounds__(256) void k_dec_scan(
    const u32* __restrict__ aTp, const float* __restrict__ eproj,
    const float* __restrict__ aW2, const u32* __restrict__ y1p,
    const float* __restrict__ zpre, const float* __restrict__ db1,
    const u16* __restrict__ decA,
    const float* __restrict__ e0c, const float* __restrict__ e1c,
    u32* __restrict__ h0p, u32* __restrict__ h1p,
    u32* __restrict__ ctxp, float* __restrict__ ctxS,
    float* __restrict__ H1all, unsigned* __restrict__ bars,
    const float* __restrict__ oW1, const float* __restrict__ ob1,
    const float* __restrict__ oW2, const float* __restrict__ ob2,
    u32* __restrict__ hidp, float* __restrict__ out){
  extern __shared__ char smem[];
  int Bid = blockIdx.x, tid = threadIdx.x;

  if (Bid < 128){
    // ================= scan block =================
    char* ldsA = smem;
    f32x4* pAc0 = (f32x4*)(smem + 65536);
    f32x4* pAc1 = (f32x4*)(smem + 65536 + 2048);
    f32x4* pB   = (f32x4*)(smem + 65536 + 4096);
    f32x4* pC   = (f32x4*)(smem + 65536 + 6144);
    float* h1s = (float*)(smem + 65536 + 8192);
    float* qs  = h1s + 512;
    float* w2s = qs + 256;
    float* es  = w2s + 256;   // 64 used
    int w = tid >> 6, l = tid & 63;
    int n_ = w & 1, kh = w >> 1;
    int lr = l & 15, lk = l >> 4;
    int idx = n_*64 + l;
    bool isRoot = (Bid == 127);
    { const uint4* s = (const uint4*)(decA + (size_t)Bid*32768);
      uint4* d4 = (uint4*)ldsA;
      for (int i = tid; i < 4096; i += 256) d4[i] = s[i]; }
    int attb = Bid >> 2, attp = Bid & 3;   // 4 blocks per batch, 64 s each
    w2s[tid] = aW2[tid];
    int u = Bid*4 + lk;
    int b_e = n_*16 + lr;
    float c0r=0.f, c1r=0.f, d0=0.f, d1=0.f, d2=0.f, d3=0.f;
    if (kh == 1){
      int dd = u >> 8, uu = u & 255;
      c0r = e0c[((size_t)dd*32 + b_e)*256 + uu];
      c1r = e1c[((size_t)dd*32 + b_e)*256 + uu];
      d0 = db1[u]; d1 = db1[512+u]; d2 = db1[1024+u]; d3 = db1[1536+u];
    }
    int brow_off = (n_*16 + lr)*256;
    __syncthreads();
    // carried h0 fragment: phase A of step t reads h0p[hp_t], which is exactly
    // what phase C of step t-1 loaded (same addresses). Init from h0p[0] (k_dinit).
    u64 qcar[16];
    {
      const u32* r0 = h0p + brow_off;
      #pragma unroll
      for (int k2 = 0; k2 < 8; k2++){
        int a = (kh*8 + k2)*16 + lk*4;
        qcar[2*k2] = ald64u(r0 + a); qcar[2*k2+1] = ald64u(r0 + a + 2);
      }
    }
    unsigned gen = 0;
    for (int t = 0; t < TD_; t++){
      int hp = t & 1;
      f32x4 rA0, rA1;
      float zp0=0.f, zp1=0.f, zp2=0.f, zp3=0.f;
      // ===== phase A: state-half partials (h0 from qcar) + attention =====
      {
        if (kh == 1){
          const float* zp = zpre + ((size_t)t*32 + b_e)*2048 + u;
          zp0 = zp[0]; zp1 = zp[512]; zp2 = zp[1024]; zp3 = zp[1536];
        }
        const u32* r1 = h1p + hp*8192 + brow_off;
        u64 qb[16];
        #pragma unroll
        for (int k2 = 0; k2 < 8; k2++){
          int a = (kh*8 + k2)*16 + lk*4;
          qb[2*k2] = ald64u(r1 + a); qb[2*k2+1] = ald64u(r1 + a + 2);
        }
        f32x4 aA = (f32x4){0.f,0.f,0.f,0.f};
        f32x4 aB = (f32x4){0.f,0.f,0.f,0.f};
        #pragma unroll
        for (int k2 = 0; k2 < 8; k2++){
          short8v aF = *(const short8v*)(ldsA + (((16 + kh*8 + k2)*64) + l)*16);
          aA = __builtin_amdgcn_mfma_f32_16x16x32_bf16(aF, mkfrag(qcar[2*k2], qcar[2*k2+1]), aA, 0, 0, 0);
        }
        #pragma unroll
        for (int k2 = 0; k2 < 8; k2++){
          short8v aF = *(const short8v*)(ldsA + (((48 + kh*8 + k2)*64) + l)*16);
          aB = __builtin_amdgcn_mfma_f32_16x16x32_bf16(aF, mkfrag(qb[2*k2], qb[2*k2+1]), aB, 0, 0, 0);
        }
        if (kh == 0){ pAc0[idx] = aA; pAc1[idx] = aB; }
        else        { rA0 = aA; rA1 = aB; }
      }
      {
        int b = attb;
        u32 hv = aldu(h1p + hp*8192 + b*256 + tid);
        h1s[2*tid] = bflo(hv); h1s[2*tid+1] = bfhi(hv);
        __syncthreads();
        // q[c] full (duplicated across the 4 blocks of this batch)
        float q0=0.f,q1=0.f,q2=0.f,q3=0.f;
        for (int j2 = 0; j2 < 256; j2 += 4){
          u32 w0 = aTp[(j2+0)*256 + tid];
          u32 w1 = aTp[(j2+1)*256 + tid];
          u32 w2 = aTp[(j2+2)*256 + tid];
          u32 w3 = aTp[(j2+3)*256 + tid];
          q0 += bflo(w0)*h1s[2*j2]   + bfhi(w0)*h1s[2*j2+1];
          q1 += bflo(w1)*h1s[2*j2+2] + bfhi(w1)*h1s[2*j2+3];
          q2 += bflo(w2)*h1s[2*j2+4] + bfhi(w2)*h1s[2*j2+5];
          q3 += bflo(w3)*h1s[2*j2+6] + bfhi(w3)*h1s[2*j2+7];
        }
        qs[tid] = (q0+q1)+(q2+q3);
        __syncthreads();
        // scores for s-quarter attp (64 s): threads = 32 sl x 8 hc
        int sl = tid >> 3, hc = tid & 7;
        #pragma unroll
        for (int so = 0; so < 2; so++){
          int s = attp*64 + so*32 + sl;
          const float4* ep = (const float4*)(eproj + ((size_t)attb*256 + s)*256 + hc*32);
          const float4* q4 = (const float4*)(qs + hc*32);
          const float4* w4 = (const float4*)(w2s + hc*32);
          float acc = 0.f;
          #pragma unroll
          for (int k = 0; k < 8; k++){
            float4 e = ep[k], qq = q4[k], ww = w4[k];
            acc += tanhf_fast(e.x+qq.x)*ww.x + tanhf_fast(e.y+qq.y)*ww.y
                 + tanhf_fast(e.z+qq.z)*ww.z + tanhf_fast(e.w+qq.w)*ww.w;
          }
          acc += __shfl_xor(acc, 1);
          acc += __shfl_xor(acc, 2);
          acc += __shfl_xor(acc, 4);
          if (hc == 0) es[so*32 + sl] = __expf(acc);
        }
        __syncthreads();
        // raw exp-weighted ctx partial (this quarter) + S
        float a0 = 0.f, a1 = 0.f, b0 = 0.f, b1 = 0.f, S = 0.f;
        size_t ybase = ((size_t)(attp*64)*32 + b)*256 + tid;
        #pragma unroll 8
        for (int si = 0; si < 64; si += 2){
          float e0 = es[si], e1 = es[si+1];
          u32 v0 = y1p[ybase + (size_t)si*8192];
          u32 v1 = y1p[ybase + (size_t)(si+1)*8192];
          S += e0 + e1;
          a0 += e0*bflo(v0); a1 += e0*bfhi(v0);
          b0 += e1*bflo(v1); b1 += e1*bfhi(v1);
        }
        astu(ctxp + attp*8192 + b*256 + tid, packbf(a0+b0, a1+b1));
        if (tid == 0) astf(ctxS + attp*32 + b, S);
      }
      icbar3(bars, ++gen, isRoot);
      // ===== phase B: ctx (4 partials, kh-split pairs) + epilogue -> h0(t+1) =====
      {
        float S0=0.f,S1=0.f,S2=0.f,S3=0.f;
        if (kh == 1){
          S0 = aldf(ctxS + b_e);      S1 = aldf(ctxS + 32 + b_e);
          S2 = aldf(ctxS + 64 + b_e); S3 = aldf(ctxS + 96 + b_e);
        }
        const u32* rcA = ctxp + (kh*2+0)*8192 + brow_off;
        const u32* rcB = ctxp + (kh*2+1)*8192 + brow_off;
        f32x4 acc = (f32x4){0.f,0.f,0.f,0.f};
        acc = mma8(ldsA, 0, rcA, 0,   lk, l, acc);
        acc = mma8(ldsA, 8, rcA, 128, lk, l, acc);
        acc = mma8(ldsA, 0, rcB, 0,   lk, l, acc);
        acc = mma8(ldsA, 8, rcB, 128, lk, l, acc);
        if (kh == 0) pB[idx] = acc;
        __syncthreads();
        if (kh == 1){
          f32x4 oc = pB[idx];
          f32x4 oh = pAc0[idx];
          float sc = 1.0f / (S0 + S1 + S2 + S3);
          float z0 = (acc[0]+oc[0])*sc + oh[0] + rA0[0] + zp0;
          float z1 = (acc[1]+oc[1])*sc + oh[1] + rA0[1] + zp1;
          float z2 = (acc[2]+oc[2])*sc + oh[2] + rA0[2] + zp2;
          float z3 = (acc[3]+oc[3])*sc + oh[3] + rA0[3] + zp3;
          float cn = sigf(z1)*c0r + sigf(z0)*tanhf_fast(z2);
          float hn = sigf(z3)*tanhf_fast(cn);
          c0r = cn;
          float other = __shfl_xor(hn, 16);
          if ((lk & 1) == 0)
            astu(h0p + (1-hp)*8192 + b_e*256 + Bid*2 + (lk>>1), packbf(hn, other));
        }
      }
      icbar3(bars, ++gen, isRoot);
      // ===== phase C: h0-half of cell1 + epilogue -> h1(t+1); carry qd -> qcar =====
      {
        const u32* rh = h0p + (1-hp)*8192 + brow_off;
        u64 qd[16];
        #pragma unroll
        for (int k2 = 0; k2 < 8; k2++){
          int a = (kh*8 + k2)*16 + lk*4;
          qd[2*k2] = ald64u(rh + a); qd[2*k2+1] = ald64u(rh + a + 2);
        }
        f32x4 acc = (f32x4){0.f,0.f,0.f,0.f};
        #pragma unroll
        for (int k2 = 0; k2 < 8; k2++){
          short8v aF = *(const short8v*)(ldsA + (((32 + kh*8 + k2)*64) + l)*16);
          acc = __builtin_amdgcn_mfma_f32_16x16x32_bf16(aF, mkfrag(qd[2*k2], qd[2*k2+1]), acc, 0, 0, 0);
        }
        #pragma unroll
        for (int i2 = 0; i2 < 16; i2++) qcar[i2] = qd[i2];
        if (kh == 0) pC[idx] = acc;
        __syncthreads();
        if (kh == 1){
          f32x4 oc = pC[idx];
          f32x4 oh = pAc1[idx];
          float z0 = acc[0] + oc[0] + oh[0] + rA1[0] + d0;
          float z1 = acc[1] + oc[1] + oh[1] + rA1[1] + d1;
          float z2 = acc[2] + oc[2] + oh[2] + rA1[2] + d2;
          float z3 = acc[3] + oc[3] + oh[3] + rA1[3] + d3;
          float cn = sigf(z1)*c1r + sigf(z0)*tanhf_fast(z2);
          float hn = sigf(z3)*tanhf_fast(cn);
          c1r = cn;
          astf(&H1all[((size_t)t*32 + b_e)*512 + u], hn);
          float other = __shfl_xor(hn, 16);
          if ((lk & 1) == 0)
            astu(h1p + (1-hp)*8192 + b_e*256 + Bid*2 + (lk>>1), packbf(hn, other));
        }
      }
      icbar3(bars, ++gen, isRoot);
    }
  } else {
    // ================= head block (c-outer, proven best) =================
    u16* As = (u16*)smem;
    u16* Bs = (u16*)(smem + 128*72*2);
    int hb = Bid - 128;
    int l = tid & 63, w = tid >> 6;
    int wr = w >> 1, wc = w & 1;
    int lr16 = l & 15, lk8 = (l >> 4) * 8;
    int r = tid >> 1, half = tid & 1;
    int cp = ((hb & 7) == 0 && (hb >> 3) < 16) ? (hb >> 3) : -1;
    for (int j = hb; j < 4000; j += 128){
      int c = j / 250, n = j % 250;
      if (cp >= 0 && cp <= c){
        unsigned need = (cp == 15) ? 189u : (unsigned)(12*cp + 12);
        if (tid == 0){
          while (aldu(bars + 1024) < need) __builtin_amdgcn_s_sleep(32);
        }
        __syncthreads();
        int rows = (cp == 15) ? 96 : 128;
        const float* Hc = H1all + (size_t)cp*128*512;
        for (int n0 = 0; n0 < 256; n0 += 128){
          f32x4 acc[4][4];
          #pragma unroll
          for (int m=0;m<4;m++)
            #pragma unroll
            for (int nn=0;nn<4;nn++) acc[m][nn] = (f32x4){0.f,0.f,0.f,0.f};
          for (int k0 = 0; k0 < 512; k0 += 64){
            u16* asd = &As[r*72 + half*32];
            if (r < rows){
              const u32* ap = (const u32*)(Hc + (size_t)r*512 + k0 + half*32);
              #pragma unroll
              for (int jj = 0; jj < 16; jj++){
                u64 v2 = ald64u(ap + 2*jj);
                asd[2*jj]   = f2bf(__uint_as_float((u32)v2));
                asd[2*jj+1] = f2bf(__uint_as_float((u32)(v2>>32)));
              }
            } else {
              #pragma unroll
              for (int jj = 0; jj < 16; jj++){ asd[2*jj]=0; asd[2*jj+1]=0; }
            }
            const float* brow = oW1 + (size_t)(n0 + r)*512 + k0 + half*32;
            u16* bsd = &Bs[r*72 + half*32];
            #pragma unroll
            for (int jj = 0; jj < 4; jj++){
              float4 p = *(const float4*)(brow + jj*8);
              float4 q = *(const float4*)(brow + jj*8 + 4);
              bsd[jj*8+0]=f2bf(p.x); bsd[jj*8+1]=f2bf(p.y); bsd[jj*8+2]=f2bf(p.z); bsd[jj*8+3]=f2bf(p.w);
              bsd[jj*8+4]=f2bf(q.x); bsd[jj*8+5]=f2bf(q.y); bsd[jj*8+6]=f2bf(q.z); bsd[jj*8+7]=f2bf(q.w);
            }
            __syncthreads();
            #pragma unroll
            for (int kk = 0; kk < 2; kk++){
              short8v aF[4], bF[4];
              #pragma unroll
              for (int m = 0; m < 4; m++)
                aF[m] = *(short8v*)&As[(wr*64 + m*16 + lr16)*72 + kk*32 + lk8];
              #pragma unroll
              for (int nn = 0; nn < 4; nn++)
                bF[nn] = *(short8v*)&Bs[(wc*64 + nn*16 + lr16)*72 + kk*32 + lk8];
              #pragma unroll
              for (int m = 0; m < 4; m++)
                #pragma unroll
                for (int nn = 0; nn < 4; nn++)
                  acc[m][nn] = __builtin_amdgcn_mfma_f32_16x16x32_bf16(aF[m], bF[nn], acc[m][nn], 0, 0, 0);
            }
            __syncthreads();
          }
          #pragma unroll
          for (int m = 0; m < 4; m++){
            int gr0 = wr*64 + m*16 + (l >> 4)*4;
            #pragma unroll
            for (int nn = 0; nn < 4; nn++){
              int gc = n0 + wc*64 + nn*16 + (l & 15);
              float bv = ob1[gc];
              #pragma unroll
              for (int j4 = 0; j4 < 4; j4++){
                int gr = gr0 + j4;
                float v = fmaxf(acc[m][nn][j4] + bv, 0.f);
                float o = __shfl_xor(v, 1);
                if ((l & 1) == 0 && gr < rows)
                  astu(hidp + (size_t)cp*16384 + gr*128 + (gc>>1), packbf(v, o));
              }
            }
          }
        }
        vdrain();
        __syncthreads();
        if (tid == 0) astu(bars + 1088 + cp, 1u);
        cp = -1;
      }
      if (tid == 0){
        while (aldu(bars + 1088 + c) == 0) __builtin_amdgcn_s_sleep(16);
      }
      __syncthreads();
      int rows = (c == 15) ? 96 : 128;
      int n0g = n * 128;
      f32x4 acc[4][4];
      #pragma unroll
      for (int m=0;m<4;m++)
        #pragma unroll
        for (int nn=0;nn<4;nn++) acc[m][nn] = (f32x4){0.f,0.f,0.f,0.f};
      const u32* hc = hidp + (size_t)c*16384;
      for (int k0 = 0; k0 < 256; k0 += 64){
        u32* asd32 = (u32*)&As[r*72 + half*32];
        if (r < rows){
          const u32* ap = hc + r*128 + (k0>>1) + half*16;
          #pragma unroll
          for (int jj = 0; jj < 8; jj++){
            u64 v2 = ald64u(ap + 2*jj);
            asd32[2*jj] = (u32)v2; asd32[2*jj+1] = (u32)(v2>>32);
          }
        } else {
          #pragma unroll
          for (int jj = 0; jj < 8; jj++){ asd32[2*jj]=0; asd32[2*jj+1]=0; }
        }
        const float* brow = oW2 + (size_t)(n0g + r)*256 + k0 + half*32;
        u16* bsd = &Bs[r*72 + half*32];
        #pragma unroll
        for (int jj = 0; jj < 4; jj++){
          float4 p = *(const float4*)(brow + jj*8);
          float4 q = *(const float4*)(brow + jj*8 + 4);
          bsd[jj*8+0]=f2bf(p.x); bsd[jj*8+1]=f2bf(p.y); bsd[jj*8+2]=f2bf(p.z); bsd[jj*8+3]=f2bf(p.w);
          bsd[jj*8+4]=f2bf(q.x); bsd[jj*8+5]=f2bf(q.y); bsd[jj*8+6]=f2bf(q.z); bsd[jj*8+7]=f2bf(q.w);
        }
        __syncthreads();
        #pragma unroll
        for (int kk = 0; kk < 2; kk++){
          short8v aF[4], bF[4];
          #pragma unroll
          for (int m = 0; m < 4; m++)
            aF[m] = *(short8v*)&As[(wr*64 + m*16 + lr16)*72 + kk*32 + lk8];
          #pragma unroll
          for (int nn = 0; nn < 4; nn++)
            bF[nn] = *(short8v*)&Bs[(wc*64 + nn*16 + lr16)*72 + kk*32 + lk8];
          #pragma unroll
          for (int m = 0; m < 4; m++)
            #pragma unroll
            for (int nn = 0; nn < 4; nn++)
              acc[m][nn] = __builtin_amdgcn_mfma_f32_16x16x32_bf16(aF[m], bF[nn], acc[m][nn], 0, 0, 0);
        }
        __syncthreads();
      }
      #pragma unroll
      for (int m = 0; m < 4; m++){
        int gr0 = wr*64 + m*16 + (l >> 4)*4;
        #pragma unroll
        for (int nn = 0; nn < 4; nn++){
          int gc = n0g + wc*64 + nn*16 + (l & 15);
          float bv = ob2[gc];
          #pragma unroll
          for (int j4 = 0; j4 < 4; j4++){
            int gr = gr0 + j4;
            if (gr < rows){
              int gt = c*4 + (gr >> 5), b = gr & 31;
              out[((size_t)(b*63 + gt))*(size_t)VV_ + gc] = acc[m][nn][j4] + bv;
            }
          }
        }
      }
    }
  }
}

// ---------------- host launch ----------------
extern "C" void kernel_launch(void* const* d_in, const int* in_sizes, int n_in,
                              void* d_out, int out_size, void* d_ws, size_t ws_size,
                              hipStream_t stream){
  (void)in_sizes; (void)n_in; (void)out_size;
  const int*   src   = (const int*)d_in[0];
  const int*   tgt   = (const int*)d_in[1];
  const float* emb   = (const float*)d_in[2];
  const float* eWih0 = (const float*)d_in[3];
  const float* eWhh0 = (const float*)d_in[4];
  const float* eb0   = (const float*)d_in[5];
  const float* eWih1 = (const float*)d_in[6];
  const float* eWhh1 = (const float*)d_in[7];
  const float* eb1   = (const float*)d_in[8];
  const float* dWih0 = (const float*)d_in[9];
  const float* dWhh0 = (const float*)d_in[10];
  const float* db0   = (const float*)d_in[11];
  const float* dWih1 = (const float*)d_in[12];
  const float* dWhh1 = (const float*)d_in[13];
  const float* db1   = (const float*)d_in[14];
  const float* aW1   = (const float*)d_in[15];
  const float* ab1   = (const float*)d_in[16];
  const float* aW2   = (const float*)d_in[17];
  const float* oW1   = (const float*)d_in[19];
  const float* ob1   = (const float*)d_in[20];
  const float* oW2   = (const float*)d_in[21];
  const float* ob2   = (const float*)d_in[22];

  float* F = (float*)d_out;
  float* W = (float*)d_ws;
  bool fused = (ws_size >= (size_t)48*1024*1024);

  float* Z     = F + OFF_Z;
  float* y0    = F + OFF_Y0;
  float* y1    = F + OFF_Y1;
  float* srcE  = F + OFF_SRCE;
  float* tgtE  = F + OFF_TGTE;
  u16*   encA0 = (u16*)(F + OFF_ENCA0);
  u16*   encA1 = (u16*)(F + OFF_ENCA1);
  float* e0h   = F + OFF_E0H;
  float* e0c   = F + OFF_E0C;
  float* e1h   = F + OFF_E1H;
  float* e1c   = F + OFF_E1C;
  u32*   hexA  = (u32*)(F + OFF_HEXA);
  u32*   hexB  = (u32*)(F + OFF_HEXB);
  unsigned* bars = (unsigned*)(F + OFF_BARS);

  float* zpre  = fused ? (W + W_ZPRE)  : (F + OFF_ZPRE);
  float* H1    = fused ? (W + W_H1ALL) : (F + OFF_H1ALL);
  float* eproj = fused ? (W + W_EPROJ) : (F + OFF_EPROJ);
  u16*   decA  = fused ? (u16*)(W + W_DECA) : (u16*)(F + OFF_DECA);
  u32*   aTp   = fused ? (u32*)(W + W_ATP)  : (u32*)(F + OFF_ATP);
  u32*   h0p   = fused ? (u32*)(W + W_H0P)  : (u32*)(F + OFF_H0P);
  u32*   h1p   = fused ? (u32*)(W + W_H1P)  : (u32*)(F + OFF_H1P);
  u32*   ctxp  = fused ? (u32*)(W + W_CTXP) : (u32*)(F + OFF_CTXP);
  float* ctxS  = fused ? (W + W_CTXS)       : (F + OFF_CTXS);
  u32*   y1p   = fused ? (u32*)(W + W_Y1P)  : (u32*)(F + OFF_Y1P);
  unsigned* dbars = fused ? (unsigned*)(W + W_DBAR) : (bars + 256);
  u32*   hidp  = fused ? (u32*)(W + W_HIDP) : (u32*)d_ws;
  float* hid   = (float*)d_ws;

  hipFuncSetAttribute((const void*)k_enc_scan, hipFuncAttributeMaxDynamicSharedMemorySize, 65536);
  hipFuncSetAttribute((const void*)k_dec_scan, hipFuncAttributeMaxDynamicSharedMemorySize, 78336);

  // zero hexp + enc/dec barrier regions
  k_zero<<<135,256,0,stream>>>(F + OFF_HEXA, 34304);
  if (fused) k_zero<<<8,256,0,stream>>>(W + W_DBAR, 2048);
  k_gather<<<((8192+2016)*32+255)/256,256,0,stream>>>(src, tgt, emb, srcE, tgtE);
  k_prep_encA<<<256,256,0,stream>>>(eWhh0, encA0);
  k_prep_encA<<<256,256,0,stream>>>(eWhh1, encA1);
  k_prep_decA<<<2048,256,0,stream>>>(dWih0, dWhh0, dWih1, dWhh1, decA);
  k_prep_aTp<<<256,256,0,stream>>>(aW1, aTp);

  // encoder layer0
  k_mgemm<<<dim3(64,16),256,0,stream>>>(srcE, eWih0, eb0, Z, 8192,2048,128, 128,0,0);
  k_enc_scan<<<32,256,65536,stream>>>(Z, encA0, y0, (u32*)nullptr, hexA, e0h, e0c, bars);
  // encoder layer1 (emits packed y1p)
  k_mgemm<<<dim3(64,16),256,0,stream>>>(y0, eWih1, eb1, Z, 8192,2048,512, 512,0,0);
  k_enc_scan<<<32,256,65536,stream>>>(Z, encA1, y1, y1p, hexB, e1h, e1c, bars + 128);

  // projections + decoder init
  k_mgemm<<<dim3(64,2),256,0,stream>>>(y1, aW1, ab1, eproj, 8192,256,512, 1024,512,4);
  k_mgemm<<<dim3(16,16),256,0,stream>>>(tgtE, dWih0, db0, zpre, 2016,2048,128, 640,0,0);
  k_dinit<<<32,256,0,stream>>>(e0h, e1h, h0p, h1p);

  // decoder (+ fused head if ws is large enough)
  int decBlocks = fused ? 256 : 128;
  k_dec_scan<<<decBlocks,256,78336,stream>>>(aTp, eproj, aW2, y1p, zpre, db1, decA,
                                             e0c, e1c, h0p, h1p, ctxp, ctxS, H1, dbars,
                                             oW1, ob1, oW2, ob2, hidp, F);

  if (!fused){
    k_mgemm<<<dim3(16,2),256,0,stream>>>(H1, oW1, ob1, hid, 2016,256,512, 512,0,1);
    k_mgemm<<<dim3(16,250),256,0,stream>>>(hid, oW2, ob2, F, 2016,32000,256, 256,0,2);
  }
}